// Round 3
// baseline (3159.312 us; speedup 1.0000x reference)
//
#include <hip/hip_runtime.h>

typedef __bf16 bf16x8 __attribute__((ext_vector_type(8)));
typedef float f32x4 __attribute__((ext_vector_type(4)));
typedef unsigned short u16;
typedef unsigned int u32;

#define T_ 64
#define B_ 1024
#define H_ 1024
#define G4_ 4096
#define HB_ (B_ * H_)
#define CHUNK_ 16

__device__ inline u16 f2bf(float f) {
  u32 u = __float_as_uint(f);
  u32 r = (u + 0x7fffu + ((u >> 16) & 1u)) >> 16;  // RNE
  return (u16)r;
}

__device__ inline uint2 cvt4(float4 v) {
  uint2 r;
  r.x = (u32)f2bf(v.x) | ((u32)f2bf(v.y) << 16);
  r.y = (u32)f2bf(v.z) | ((u32)f2bf(v.w) << 16);
  return r;
}

__device__ __forceinline__ void gload16(const void* g, void* l) {
  __builtin_amdgcn_global_load_lds(
      (const __attribute__((address_space(1))) unsigned int*)g,
      (__attribute__((address_space(3))) unsigned int*)l, 16, 0, 0);
}

__device__ inline float fsig(float x) { return 1.f / (1.f + __expf(-x)); }
__device__ inline float ftanh(float x) {
  float e = __expf(2.f * x);
  return 1.f - 2.f / (e + 1.f);
}

// ---------- prep: WihP/WhhP gate-interleaved-row bf16 [4096][1024], bcP permuted bias,
// hb0=bf16(h0), c=c0, logits[2][1024][2]=bout.
// Permutation: n' = (j>>4)*64 + gate*16 + (j&15)
__global__ void prep_kernel(const float* __restrict__ W_ih, const float* __restrict__ W_hh,
                            const float* __restrict__ b_ih, const float* __restrict__ b_hh,
                            const float* __restrict__ h0, const float* __restrict__ c0,
                            const float* __restrict__ bout,
                            u16* __restrict__ WihP, u16* __restrict__ WhhP,
                            float* __restrict__ bcP, u16* __restrict__ hb0,
                            float* __restrict__ c, float* __restrict__ logits) {
  int bid = blockIdx.x, tid = threadIdx.x;
  if (bid < 4096) {
    int np = bid;
    int gate = (np >> 4) & 3;
    int j = ((np >> 6) << 4) | (np & 15);
    size_t srow = (size_t)(gate * 1024 + j) * 1024;
    int base = tid << 2;
    *(uint2*)(WihP + (size_t)np * 1024 + base) = cvt4(*(const float4*)(W_ih + srow + base));
    *(uint2*)(WhhP + (size_t)np * 1024 + base) = cvt4(*(const float4*)(W_hh + srow + base));
  } else if (bid < 5120) {
    int i = ((bid - 4096) * 256 + tid) << 2;
    *(float4*)(c + i) = *(const float4*)(c0 + i);
    *(uint2*)(hb0 + i) = cvt4(*(const float4*)(h0 + i));
  } else if (bid == 5120) {
#pragma unroll
    for (int q = 0; q < 16; ++q) {
      int np = q * 256 + tid;
      int gate = (np >> 4) & 3;
      int j = ((np >> 6) << 4) | (np & 15);
      int srcn = gate * 1024 + j;
      bcP[np] = b_ih[srcn] + b_hh[srcn];
    }
  } else {
#pragma unroll
    for (int q = 0; q < 16; ++q) {
      int i = q * 256 + tid;  // 2 bufs * 1024 b * 2 cls
      logits[i] = bout[i & 1];
    }
  }
}

// ---------- gather one chunk of 16 steps: XEc[tc][b][:] = bf16(emb[x[b, t0+tc]])
__global__ void gather_kernel(const int* __restrict__ x, const float* __restrict__ emb,
                              u16* __restrict__ XEc, int t0) {
  int b = blockIdx.x, tc = blockIdx.y;
  int row = x[b * T_ + t0 + tc];
  int e = threadIdx.x << 2;
  float4 v = *(const float4*)(emb + (size_t)row * H_ + e);
  *(uint2*)(XEc + ((size_t)tc * B_ + b) * H_ + e) = cvt4(v);
}

// ---------- x-projection big GEMM (m97-style 128x128, 4 waves of 64x64, BK=64):
// GXc[gm][n'] = bf16( XEc[gm] . WihP[n'] + bcP[n'] ),  M = 16*1024, N = 4096, K = 1024.
__global__ void __launch_bounds__(256, 2) xproj_kernel(
    const u16* __restrict__ XEc, const u16* __restrict__ WihP,
    const float* __restrict__ bcP, u16* __restrict__ GXc) {
  __shared__ char smem[32768];  // lsA [128][128B] + lsB [128][128B]
  const int tid = threadIdx.x;
  const int lane = tid & 63;
  const int wave = tid >> 6;
  const int wm = wave >> 1, wn = wave & 1;
  // XCD swizzle: each XCD owns 4 consecutive n-tiles (1MB of W -> L2-resident)
  int hbid = blockIdx.x;
  int L = (hbid & 7) * 512 + (hbid >> 3);
  const int n0 = (L >> 7) * 128;   // 32 n-tiles
  const int m0 = (L & 127) * 128;  // 128 m-tiles

  const u16* srcA[4];
  const u16* srcB[4];
  int betaA[4], betaB[4];
#pragma unroll
  for (int s = 0; s < 4; ++s) {
    int beta = (s * 256 + tid) * 16;             // 0..16K
    int row = beta >> 7;                         // 128B rows
    int colu = (beta & 127) ^ ((row & 7) << 4);  // pre-swizzled source col
    int kl = colu >> 1;
    srcA[s] = XEc + (size_t)(m0 + row) * 1024 + kl;
    srcB[s] = WihP + (size_t)(n0 + row) * 1024 + kl;
    betaA[s] = beta;
    betaB[s] = 16384 + beta;
  }

  f32x4 acc[4][4] = {};
  const int rsel = lane & 15;
  const int ksel = (lane >> 4) << 4;

  for (int kt = 0; kt < 16; ++kt) {
#pragma unroll
    for (int s = 0; s < 4; ++s) gload16(srcA[s], smem + betaA[s]);
#pragma unroll
    for (int s = 0; s < 4; ++s) gload16(srcB[s], smem + betaB[s]);
#pragma unroll
    for (int s = 0; s < 4; ++s) { srcA[s] += 64; srcB[s] += 64; }
    __syncthreads();
#pragma unroll
    for (int kk = 0; kk < 2; ++kk) {
      const int colb = kk * 64 + ksel;
      bf16x8 af[4], bfr[4];
#pragma unroll
      for (int mi = 0; mi < 4; ++mi) {
        int row = wm * 64 + mi * 16 + rsel;
        af[mi] = *(const bf16x8*)(smem + row * 128 + (colb ^ ((row & 7) << 4)));
      }
#pragma unroll
      for (int ni = 0; ni < 4; ++ni) {
        int row = wn * 64 + ni * 16 + rsel;
        bfr[ni] = *(const bf16x8*)(smem + 16384 + row * 128 + (colb ^ ((row & 7) << 4)));
      }
#pragma unroll
      for (int mi = 0; mi < 4; ++mi)
#pragma unroll
        for (int ni = 0; ni < 4; ++ni)
          acc[mi][ni] = __builtin_amdgcn_mfma_f32_16x16x32_bf16(af[mi], bfr[ni], acc[mi][ni], 0, 0, 0);
    }
    __syncthreads();
  }

  const int rbase = (lane >> 4) << 2;
  const int cbase = lane & 15;
  float bc[4];
#pragma unroll
  for (int ni = 0; ni < 4; ++ni) bc[ni] = bcP[n0 + wn * 64 + ni * 16 + cbase];
#pragma unroll
  for (int mi = 0; mi < 4; ++mi) {
#pragma unroll
    for (int ni = 0; ni < 4; ++ni) {
      int gc = n0 + wn * 64 + ni * 16 + cbase;
#pragma unroll
      for (int r = 0; r < 4; ++r) {
        int gm = m0 + wm * 64 + mi * 16 + rbase + r;
        GXc[(size_t)gm * G4_ + gc] = f2bf(acc[mi][ni][r] + bc[ni]);
      }
    }
  }
}

// ---------- recurrent step: gates = GX(t) [acc-init] + hbR @ WhhP^T, fused LSTM cell,
// head partials via atomicAdd, finalize of previous step's logits.
// BM=128, BN=64, 4 waves = (qm M-half, kh K-half of 1024), 8 kt iters of BK=64/half.
__global__ void __launch_bounds__(256, 2) rec_kernel(
    const u16* __restrict__ hbR, const u16* __restrict__ WhhP,
    const u16* __restrict__ GXt, float* __restrict__ c, u16* __restrict__ hbW,
    float* __restrict__ logits, const float* __restrict__ Wout,
    const float* __restrict__ bout, float* __restrict__ out, int t) {
  __shared__ char smem[49152];  // 32KB lsA + 16KB lsB; overlaid by 32KB lsX f32
  const int tid = threadIdx.x;
  const int lane = tid & 63;
  const int wave = tid >> 6;
  const int qm = wave >> 1;
  const int kh = wave & 1;
  int hbid = blockIdx.x;
  int L = (hbid & 7) * 64 + (hbid >> 3);  // XCD swizzle (512 blocks, 64/XCD)
  const int bx = L >> 3;                  // n-tile: 8 per XCD -> 1MB W L2-resident
  const int by = L & 7;
  const int n0 = bx * 64;
  const int m0 = by * 128;

  // finalize previous step's head: log-softmax + buffer reset (off critical path)
  if (t > 0 && bx == 0 && by < 4) {
    int b = by * 256 + tid;
    float* Lp = logits + ((t - 1) & 1) * 2048 + b * 2;
    float l0 = Lp[0], l1 = Lp[1];
    float m = fmaxf(l0, l1);
    float ls = m + __logf(__expf(l0 - m) + __expf(l1 - m));
    float* op = out + (size_t)(t - 1) * (B_ * 2) + b * 2;
    op[0] = l0 - ls;
    op[1] = l1 - ls;
    Lp[0] = bout[0];
    Lp[1] = bout[1];
  }

  const u16* srcA[8];
  const u16* srcB[4];
  int betaA[8], betaB[4];
#pragma unroll
  for (int s = 0; s < 8; ++s) {
    int beta = (s * 256 + tid) * 16;  // A: 32KB, rows [128][256B] = 2 K-halves x 64
    int row = beta >> 8;
    int colu = (beta & 255) ^ ((row & 7) << 4);
    int half = colu >> 7;
    int kl = (colu & 127) >> 1;
    srcA[s] = hbR + (size_t)(m0 + row) * 1024 + half * 512 + kl;
    betaA[s] = beta;
  }
#pragma unroll
  for (int s = 0; s < 4; ++s) {
    int beta = (s * 256 + tid) * 16;  // B: 16KB, rows [64][256B]
    int row = beta >> 8;
    int colu = (beta & 255) ^ ((row & 7) << 4);
    int half = colu >> 7;
    int kl = (colu & 127) >> 1;
    srcB[s] = WhhP + (size_t)(n0 + row) * 1024 + half * 512 + kl;
    betaB[s] = 32768 + beta;
  }

  const int rbase = (lane >> 4) << 2;
  const int cbase = lane & 15;
  f32x4 acc[4][4];
  if (kh == 0) {  // init accumulator with x-projection (+bias, folded in GX)
#pragma unroll
    for (int mi = 0; mi < 4; ++mi)
#pragma unroll
      for (int ni = 0; ni < 4; ++ni)
#pragma unroll
        for (int r = 0; r < 4; ++r) {
          int gm = m0 + qm * 64 + mi * 16 + rbase + r;
          int gc = n0 + ni * 16 + cbase;
          acc[mi][ni][r] = __uint_as_float((u32)GXt[(size_t)gm * G4_ + gc] << 16);
        }
  } else {
#pragma unroll
    for (int mi = 0; mi < 4; ++mi)
#pragma unroll
      for (int ni = 0; ni < 4; ++ni)
        acc[mi][ni] = f32x4{0.f, 0.f, 0.f, 0.f};
  }

  const int kbase = kh << 7;
  const int rsel = lane & 15;
  const int ksel = (lane >> 4) << 4;

  for (int kt = 0; kt < 8; ++kt) {
#pragma unroll
    for (int s = 0; s < 8; ++s) gload16(srcA[s], smem + betaA[s]);
#pragma unroll
    for (int s = 0; s < 4; ++s) gload16(srcB[s], smem + betaB[s]);
#pragma unroll
    for (int s = 0; s < 8; ++s) srcA[s] += 64;
#pragma unroll
    for (int s = 0; s < 4; ++s) srcB[s] += 64;
    __syncthreads();
#pragma unroll
    for (int kk = 0; kk < 2; ++kk) {
      const int colb = kbase + kk * 64 + ksel;
      bf16x8 af[4], bfr[4];
#pragma unroll
      for (int mi = 0; mi < 4; ++mi) {
        int row = qm * 64 + mi * 16 + rsel;
        af[mi] = *(const bf16x8*)(smem + row * 256 + (colb ^ ((row & 7) << 4)));
      }
#pragma unroll
      for (int ni = 0; ni < 4; ++ni) {
        int row = ni * 16 + rsel;
        bfr[ni] = *(const bf16x8*)(smem + 32768 + row * 256 + (colb ^ ((row & 7) << 4)));
      }
#pragma unroll
      for (int mi = 0; mi < 4; ++mi)
#pragma unroll
        for (int ni = 0; ni < 4; ++ni)
          acc[mi][ni] = __builtin_amdgcn_mfma_f32_16x16x32_bf16(af[mi], bfr[ni], acc[mi][ni], 0, 0, 0);
    }
    __syncthreads();
  }

  // combine K-halves + LSTM cell + head partials
  float* lsX = (float*)smem;  // [2][64][64] f32
  if (kh == 1) {
#pragma unroll
    for (int mi = 0; mi < 4; ++mi)
#pragma unroll
      for (int ni = 0; ni < 4; ++ni)
#pragma unroll
        for (int r = 0; r < 4; ++r)
          lsX[qm * 4096 + (mi * 16 + rbase + r) * 64 + ni * 16 + cbase] = acc[mi][ni][r];
  }
  __syncthreads();
  if (kh == 0) {
    const int j = bx * 16 + cbase;
    const float w0 = Wout[j], w1 = Wout[1024 + j];
    float* Lc = logits + (t & 1) * 2048;
#pragma unroll
    for (int mi = 0; mi < 4; ++mi) {
#pragma unroll
      for (int r = 0; r < 4; ++r) {
        int rl = mi * 16 + rbase + r;
        int b = m0 + qm * 64 + rl;
        int xb = qm * 4096 + rl * 64 + cbase;
        float gi = acc[mi][0][r] + lsX[xb];
        float gf = acc[mi][1][r] + lsX[xb + 16];
        float gg = acc[mi][2][r] + lsX[xb + 32];
        float go = acc[mi][3][r] + lsX[xb + 48];
        size_t idx = (size_t)b * H_ + j;
        float c2 = fsig(gf) * c[idx] + fsig(gi) * ftanh(gg);
        float h2 = fsig(go) * ftanh(c2);
        c[idx] = c2;
        hbW[idx] = f2bf(h2);
        float p0 = c2 * w0, p1 = c2 * w1;
#pragma unroll
        for (int off = 1; off < 16; off <<= 1) {
          p0 += __shfl_xor(p0, off);
          p1 += __shfl_xor(p1, off);
        }
        if (cbase == 0) {
          atomicAdd(&Lc[b * 2], p0);
          atomicAdd(&Lc[b * 2 + 1], p1);
        }
      }
    }
  }
}

// ---------- final: out_final = cT.Wout + bout (raw) AND out[63] = logsoftmax(same)
__global__ void final_kernel(const float* __restrict__ c, const float* __restrict__ Wout,
                             const float* __restrict__ bout, float* __restrict__ out) {
  int b = blockIdx.x, tid = threadIdx.x;
  float a0 = 0.f, a1 = 0.f;
#pragma unroll
  for (int q = 0; q < 4; ++q) {
    int jj = q * 256 + tid;
    float cv = c[(size_t)b * H_ + jj];
    a0 += cv * Wout[jj];
    a1 += cv * Wout[1024 + jj];
  }
#pragma unroll
  for (int off = 32; off; off >>= 1) {
    a0 += __shfl_down(a0, off);
    a1 += __shfl_down(a1, off);
  }
  __shared__ float red[8];
  if ((tid & 63) == 0) { red[tid >> 6] = a0; red[4 + (tid >> 6)] = a1; }
  __syncthreads();
  if (tid == 0) {
    float l0 = red[0] + red[1] + red[2] + red[3] + bout[0];
    float l1 = red[4] + red[5] + red[6] + red[7] + bout[1];
    out[(size_t)T_ * (B_ * 2) + b * 2 + 0] = l0;
    out[(size_t)T_ * (B_ * 2) + b * 2 + 1] = l1;
    float m = fmaxf(l0, l1);
    float ls = m + __logf(__expf(l0 - m) + __expf(l1 - m));
    out[(size_t)63 * (B_ * 2) + b * 2 + 0] = l0 - ls;
    out[(size_t)63 * (B_ * 2) + b * 2 + 1] = l1 - ls;
  }
}

extern "C" void kernel_launch(void* const* d_in, const int* in_sizes, int n_in,
                              void* d_out, int out_size, void* d_ws, size_t ws_size,
                              hipStream_t stream) {
  const int* x      = (const int*)d_in[0];
  const float* emb  = (const float*)d_in[1];
  const float* W_ih = (const float*)d_in[2];
  const float* W_hh = (const float*)d_in[3];
  const float* b_ih = (const float*)d_in[4];
  const float* b_hh = (const float*)d_in[5];
  const float* W_out = (const float*)d_in[6];
  const float* b_out = (const float*)d_in[7];
  const float* h0   = (const float*)d_in[8];
  const float* c0   = (const float*)d_in[9];
  float* out = (float*)d_out;

  // workspace (~193 MB; poison fills show d_ws >= 800MB)
  char* w = (char*)d_ws;
  u16* WihP = (u16*)w;   w += (size_t)G4_ * H_ * 2;             // 8 MB
  u16* WhhP = (u16*)w;   w += (size_t)G4_ * H_ * 2;             // 8 MB
  u16* XEc  = (u16*)w;   w += (size_t)CHUNK_ * HB_ * 2;         // 32 MB
  u16* GXc  = (u16*)w;   w += (size_t)CHUNK_ * B_ * G4_ * 2;    // 128 MB
  float* c  = (float*)w; w += (size_t)HB_ * 4;                  // 4 MB
  u16* hb   = (u16*)w;   w += (size_t)2 * HB_ * 2;              // 4 MB
  float* bcP = (float*)w;    w += (size_t)G4_ * 4;
  float* logits = (float*)w; w += (size_t)2 * B_ * 2 * 4;

  prep_kernel<<<5122, 256, 0, stream>>>(W_ih, W_hh, b_ih, b_hh, h0, c0, b_out,
                                        WihP, WhhP, bcP, hb, c, logits);
  for (int ch = 0; ch < T_ / CHUNK_; ++ch) {
    gather_kernel<<<dim3(B_, CHUNK_), 256, 0, stream>>>(x, emb, XEc, ch * CHUNK_);
    xproj_kernel<<<4096, 256, 0, stream>>>(XEc, WihP, bcP, GXc);
    for (int tc = 0; tc < CHUNK_; ++tc) {
      int t = ch * CHUNK_ + tc;
      u16* hbR = hb + (size_t)(t & 1) * HB_;
      u16* hbW = hb + (size_t)((t + 1) & 1) * HB_;
      rec_kernel<<<512, 256, 0, stream>>>(hbR, WhhP, GXc + (size_t)tc * B_ * G4_,
                                          c, hbW, logits, W_out, b_out, out, t);
    }
  }
  final_kernel<<<1024, 256, 0, stream>>>(c, W_out, b_out, out);
}

// Round 4
// 2002.684 us; speedup vs baseline: 1.5775x; 1.5775x over previous
//
#include <hip/hip_runtime.h>

typedef __bf16 bf16x8 __attribute__((ext_vector_type(8)));
typedef float f32x4 __attribute__((ext_vector_type(4)));
typedef unsigned short u16;
typedef unsigned int u32;

#define T_ 64
#define B_ 1024
#define H_ 1024
#define G4_ 4096
#define HB_ (B_ * H_)
#define CHUNK_ 16

__device__ inline u16 f2bf(float f) {
  u32 u = __float_as_uint(f);
  u32 r = (u + 0x7fffu + ((u >> 16) & 1u)) >> 16;  // RNE
  return (u16)r;
}

__device__ inline uint2 cvt4(float4 v) {
  uint2 r;
  r.x = (u32)f2bf(v.x) | ((u32)f2bf(v.y) << 16);
  r.y = (u32)f2bf(v.z) | ((u32)f2bf(v.w) << 16);
  return r;
}

__device__ __forceinline__ void gload16(const void* g, void* l) {
  __builtin_amdgcn_global_load_lds(
      (const __attribute__((address_space(1))) unsigned int*)g,
      (__attribute__((address_space(3))) unsigned int*)l, 16, 0, 0);
}

__device__ inline float fsig(float x) { return 1.f / (1.f + __expf(-x)); }
__device__ inline float ftanh(float x) {
  float e = __expf(2.f * x);
  return 1.f - 2.f / (e + 1.f);
}

// ---------- prep: WihP/WhhP gate-interleaved-row bf16 [4096][1024], bcP permuted bias,
// hb0=bf16(h0), c=c0.  Permutation: n' = (j>>4)*64 + gate*16 + (j&15)
__global__ void prep_kernel(const float* __restrict__ W_ih, const float* __restrict__ W_hh,
                            const float* __restrict__ b_ih, const float* __restrict__ b_hh,
                            const float* __restrict__ h0, const float* __restrict__ c0,
                            u16* __restrict__ WihP, u16* __restrict__ WhhP,
                            float* __restrict__ bcP, u16* __restrict__ hb0,
                            float* __restrict__ c) {
  int bid = blockIdx.x, tid = threadIdx.x;
  if (bid < 4096) {
    int np = bid;
    int gate = (np >> 4) & 3;
    int j = ((np >> 6) << 4) | (np & 15);
    size_t srow = (size_t)(gate * 1024 + j) * 1024;
    int base = tid << 2;
    *(uint2*)(WihP + (size_t)np * 1024 + base) = cvt4(*(const float4*)(W_ih + srow + base));
    *(uint2*)(WhhP + (size_t)np * 1024 + base) = cvt4(*(const float4*)(W_hh + srow + base));
  } else if (bid < 5120) {
    int i = ((bid - 4096) * 256 + tid) << 2;
    *(float4*)(c + i) = *(const float4*)(c0 + i);
    *(uint2*)(hb0 + i) = cvt4(*(const float4*)(h0 + i));
  } else {
#pragma unroll
    for (int q = 0; q < 16; ++q) {
      int np = q * 256 + tid;
      int gate = (np >> 4) & 3;
      int j = ((np >> 6) << 4) | (np & 15);
      int srcn = gate * 1024 + j;
      bcP[np] = b_ih[srcn] + b_hh[srcn];
    }
  }
}

// ---------- gather one chunk of 16 steps: XEc[tc][b][:] = bf16(emb[x[b, t0+tc]])
__global__ void gather_kernel(const int* __restrict__ x, const float* __restrict__ emb,
                              u16* __restrict__ XEc, int t0) {
  int b = blockIdx.x, tc = blockIdx.y;
  int row = x[b * T_ + t0 + tc];
  int e = threadIdx.x << 2;
  float4 v = *(const float4*)(emb + (size_t)row * H_ + e);
  *(uint2*)(XEc + ((size_t)tc * B_ + b) * H_ + e) = cvt4(v);
}

// ---------- x-projection big GEMM (128x128, 4 waves of 64x64, BK=64):
// GXc[gm][n'] = bf16( XEc[gm] . WihP[n'] + bcP[n'] ),  M = 16*1024, N = 4096, K = 1024.
// XCD mapping: each XCD owns an M-slice (A read once); n-outer/m-inner keeps the
// 256KB B-panel L2-resident while 16 m-blocks consume it.
__global__ void __launch_bounds__(256, 2) xproj_kernel(
    const u16* __restrict__ XEc, const u16* __restrict__ WihP,
    const float* __restrict__ bcP, u16* __restrict__ GXc) {
  __shared__ char smem[32768];  // lsA [128][128B] + lsB [128][128B]
  const int tid = threadIdx.x;
  const int lane = tid & 63;
  const int wave = tid >> 6;
  const int wm = wave >> 1, wn = wave & 1;
  const int hbid = blockIdx.x;          // 4096 = 8 XCD x 512
  const int xcd = hbid & 7;
  const int s9 = hbid >> 3;             // [0,512)
  const int n0 = (s9 >> 4) * 128;       // n-outer: 32 n-tiles
  const int m0 = (xcd * 16 + (s9 & 15)) * 128;  // XCD-private M slice, m-inner

  const u16* srcA[4];
  const u16* srcB[4];
  int betaA[4], betaB[4];
#pragma unroll
  for (int s = 0; s < 4; ++s) {
    int beta = (s * 256 + tid) * 16;             // 0..16K
    int row = beta >> 7;                         // 128B rows
    int colu = (beta & 127) ^ ((row & 7) << 4);  // pre-swizzled source col
    int kl = colu >> 1;
    srcA[s] = XEc + (size_t)(m0 + row) * 1024 + kl;
    srcB[s] = WihP + (size_t)(n0 + row) * 1024 + kl;
    betaA[s] = beta;
    betaB[s] = 16384 + beta;
  }

  f32x4 acc[4][4] = {};
  const int rsel = lane & 15;
  const int ksel = (lane >> 4) << 4;

  for (int kt = 0; kt < 16; ++kt) {
#pragma unroll
    for (int s = 0; s < 4; ++s) gload16(srcA[s], smem + betaA[s]);
#pragma unroll
    for (int s = 0; s < 4; ++s) gload16(srcB[s], smem + betaB[s]);
#pragma unroll
    for (int s = 0; s < 4; ++s) { srcA[s] += 64; srcB[s] += 64; }
    __syncthreads();
#pragma unroll
    for (int kk = 0; kk < 2; ++kk) {
      const int colb = kk * 64 + ksel;
      bf16x8 af[4], bfr[4];
#pragma unroll
      for (int mi = 0; mi < 4; ++mi) {
        int row = wm * 64 + mi * 16 + rsel;
        af[mi] = *(const bf16x8*)(smem + row * 128 + (colb ^ ((row & 7) << 4)));
      }
#pragma unroll
      for (int ni = 0; ni < 4; ++ni) {
        int row = wn * 64 + ni * 16 + rsel;
        bfr[ni] = *(const bf16x8*)(smem + 16384 + row * 128 + (colb ^ ((row & 7) << 4)));
      }
#pragma unroll
      for (int mi = 0; mi < 4; ++mi)
#pragma unroll
        for (int ni = 0; ni < 4; ++ni)
          acc[mi][ni] = __builtin_amdgcn_mfma_f32_16x16x32_bf16(af[mi], bfr[ni], acc[mi][ni], 0, 0, 0);
    }
    __syncthreads();
  }

  const int rbase = (lane >> 4) << 2;
  const int cbase = lane & 15;
  float bc[4];
#pragma unroll
  for (int ni = 0; ni < 4; ++ni) bc[ni] = bcP[n0 + wn * 64 + ni * 16 + cbase];
#pragma unroll
  for (int mi = 0; mi < 4; ++mi) {
#pragma unroll
    for (int ni = 0; ni < 4; ++ni) {
      int gc = n0 + wn * 64 + ni * 16 + cbase;
#pragma unroll
      for (int r = 0; r < 4; ++r) {
        int gm = m0 + wm * 64 + mi * 16 + rbase + r;
        GXc[(size_t)gm * G4_ + gc] = f2bf(acc[mi][ni][r] + bc[ni]);
      }
    }
  }
}

// ---------- recurrent step: gates = GX(t) [LDS-staged] + hbR @ WhhP^T, fused cell,
// head partials -> part[b][cls][bx]; previous step finalized at kernel end (by==0).
// BM=128, BN=64, 4 waves = (qm M-half, kh K-half of 1024), 8 kt iters.
__global__ void __launch_bounds__(256, 2) rec_kernel(
    const u16* __restrict__ hbR, const u16* __restrict__ WhhP,
    const u16* __restrict__ GXt, float* __restrict__ c, u16* __restrict__ hbW,
    float* __restrict__ partW, const float* __restrict__ partR,
    const float* __restrict__ Wout, const float* __restrict__ bout,
    float* __restrict__ out, int t) {
  __shared__ char smem[65536];  // 32KB lsA + 16KB lsB + 16KB lsGX; lsX overlays lsA
  const int tid = threadIdx.x;
  const int lane = tid & 63;
  const int wave = tid >> 6;
  const int qm = wave >> 1;
  const int kh = wave & 1;
  const int hbid = blockIdx.x;
  const int L = (hbid & 7) * 64 + (hbid >> 3);  // XCD swizzle: W n-slice per XCD
  const int bx = L >> 3;   // [0,64): n-tile
  const int by = L & 7;    // [0,8): m-tile
  const int n0 = bx * 64;
  const int m0 = by * 128;

  // stage GX tile [128 rows][64 cols] bf16 -> lsGX (swizzled via source)
#pragma unroll
  for (int s = 0; s < 4; ++s) {
    int beta = (s * 256 + tid) * 16;             // 0..16K
    int row = beta >> 7;
    int colu = (beta & 127) ^ ((row & 7) << 4);
    gload16(GXt + (size_t)(m0 + row) * G4_ + n0 + (colu >> 1), smem + 49152 + beta);
  }

  const u16* srcA[8];
  const u16* srcB[4];
  int betaA[8], betaB[4];
#pragma unroll
  for (int s = 0; s < 8; ++s) {
    int beta = (s * 256 + tid) * 16;  // A: 32KB, rows [128][256B] = 2 K-halves x 128B
    int row = beta >> 8;
    int colu = (beta & 255) ^ ((row & 7) << 4);
    int half = colu >> 7;
    int kl = (colu & 127) >> 1;
    srcA[s] = hbR + (size_t)(m0 + row) * 1024 + half * 512 + kl;
    betaA[s] = beta;
  }
#pragma unroll
  for (int s = 0; s < 4; ++s) {
    int beta = (s * 256 + tid) * 16;  // B: 16KB, rows [64][256B]
    int row = beta >> 8;
    int colu = (beta & 255) ^ ((row & 7) << 4);
    int half = colu >> 7;
    int kl = (colu & 127) >> 1;
    srcB[s] = WhhP + (size_t)(n0 + row) * 1024 + half * 512 + kl;
    betaB[s] = 32768 + beta;
  }

  f32x4 acc[4][4] = {};
  const int kbase = kh << 7;
  const int rsel = lane & 15;
  const int ksel = (lane >> 4) << 4;

  for (int kt = 0; kt < 8; ++kt) {
#pragma unroll
    for (int s = 0; s < 8; ++s) gload16(srcA[s], smem + betaA[s]);
#pragma unroll
    for (int s = 0; s < 4; ++s) gload16(srcB[s], smem + betaB[s]);
#pragma unroll
    for (int s = 0; s < 8; ++s) srcA[s] += 64;
#pragma unroll
    for (int s = 0; s < 4; ++s) srcB[s] += 64;
    __syncthreads();
#pragma unroll
    for (int kk = 0; kk < 2; ++kk) {
      const int colb = kbase + kk * 64 + ksel;
      bf16x8 af[4], bfr[4];
#pragma unroll
      for (int mi = 0; mi < 4; ++mi) {
        int row = qm * 64 + mi * 16 + rsel;
        af[mi] = *(const bf16x8*)(smem + row * 256 + (colb ^ ((row & 7) << 4)));
      }
#pragma unroll
      for (int ni = 0; ni < 4; ++ni) {
        int row = ni * 16 + rsel;
        bfr[ni] = *(const bf16x8*)(smem + 32768 + row * 256 + (colb ^ ((row & 7) << 4)));
      }
#pragma unroll
      for (int mi = 0; mi < 4; ++mi)
#pragma unroll
        for (int ni = 0; ni < 4; ++ni)
          acc[mi][ni] = __builtin_amdgcn_mfma_f32_16x16x32_bf16(af[mi], bfr[ni], acc[mi][ni], 0, 0, 0);
    }
    __syncthreads();
  }

  // combine K-halves + GX + LSTM cell + head partials
  float* lsX = (float*)smem;            // [2][64][64] f32 (overlays lsA+lsB)
  const char* lsGX = smem + 49152;
  const int rbase = (lane >> 4) << 2;
  const int cbase = lane & 15;
  if (kh == 1) {
#pragma unroll
    for (int mi = 0; mi < 4; ++mi)
#pragma unroll
      for (int ni = 0; ni < 4; ++ni)
#pragma unroll
        for (int r = 0; r < 4; ++r)
          lsX[qm * 4096 + (mi * 16 + rbase + r) * 64 + ni * 16 + cbase] = acc[mi][ni][r];
  }
  __syncthreads();
  if (kh == 0) {
    const int j = bx * 16 + cbase;
    const float w0 = Wout[j], w1 = Wout[1024 + j];
#pragma unroll
    for (int mi = 0; mi < 4; ++mi) {
#pragma unroll
      for (int r = 0; r < 4; ++r) {
        int rl = mi * 16 + rbase + r;
        int grow = qm * 64 + rl;        // row within 128-tile
        int b = m0 + grow;
        int xb = qm * 4096 + rl * 64 + cbase;
        int gxswz = (grow & 7) << 4;
        float gx0 = __uint_as_float(
            (u32)*(const u16*)(lsGX + ((grow << 7) | (((cbase << 1) ^ gxswz)))) << 16);
        float gx1 = __uint_as_float(
            (u32)*(const u16*)(lsGX + ((grow << 7) | ((((16 + cbase) << 1) ^ gxswz)))) << 16);
        float gx2 = __uint_as_float(
            (u32)*(const u16*)(lsGX + ((grow << 7) | ((((32 + cbase) << 1) ^ gxswz)))) << 16);
        float gx3 = __uint_as_float(
            (u32)*(const u16*)(lsGX + ((grow << 7) | ((((48 + cbase) << 1) ^ gxswz)))) << 16);
        float gi = acc[mi][0][r] + lsX[xb] + gx0;
        float gf = acc[mi][1][r] + lsX[xb + 16] + gx1;
        float gg = acc[mi][2][r] + lsX[xb + 32] + gx2;
        float go = acc[mi][3][r] + lsX[xb + 48] + gx3;
        size_t idx = (size_t)b * H_ + j;
        float c2 = fsig(gf) * c[idx] + fsig(gi) * ftanh(gg);
        float h2 = fsig(go) * ftanh(c2);
        c[idx] = c2;
        hbW[idx] = f2bf(h2);
        float p0 = c2 * w0, p1 = c2 * w1;
#pragma unroll
        for (int off = 1; off < 16; off <<= 1) {
          p0 += __shfl_xor(p0, off);
          p1 += __shfl_xor(p1, off);
        }
        if (cbase == 0) {
          partW[(b << 7) + bx] = p0;
          partW[(b << 7) + 64 + bx] = p1;
        }
      }
    }
  }

  // finalize previous step's head (off critical path, spread across XCDs via by==0)
  if (t > 0 && by == 0 && tid < 32) {
    int b = bx * 16 + (tid >> 1);
    int cls = tid & 1;
    const float4* pp = (const float4*)(partR + (b << 7) + cls * 64);
    float4 sv = {0.f, 0.f, 0.f, 0.f};
#pragma unroll
    for (int q = 0; q < 16; ++q) {
      float4 v = pp[q];
      sv.x += v.x; sv.y += v.y; sv.z += v.z; sv.w += v.w;
    }
    float l = sv.x + sv.y + sv.z + sv.w + bout[cls];
    float other = __shfl_xor(l, 1);
    float m = fmaxf(l, other);
    float ls = m + __logf(__expf(l - m) + __expf(other - m));
    out[(size_t)(t - 1) * (B_ * 2) + b * 2 + cls] = l - ls;
  }
}

// ---------- final: reduce step-63 partials -> out[63] (log-softmax) + out_final (raw)
__global__ void final_kernel(const float* __restrict__ partR, const float* __restrict__ bout,
                             float* __restrict__ out) {
  int gid = blockIdx.x * 256 + threadIdx.x;  // 2048 = 1024 b x 2 cls
  int b = gid >> 1, cls = gid & 1;
  const float4* pp = (const float4*)(partR + (b << 7) + cls * 64);
  float4 sv = {0.f, 0.f, 0.f, 0.f};
#pragma unroll
  for (int q = 0; q < 16; ++q) {
    float4 v = pp[q];
    sv.x += v.x; sv.y += v.y; sv.z += v.z; sv.w += v.w;
  }
  float l = sv.x + sv.y + sv.z + sv.w + bout[cls];
  out[(size_t)T_ * (B_ * 2) + b * 2 + cls] = l;  // out_final raw
  float other = __shfl_xor(l, 1);
  float m = fmaxf(l, other);
  float ls = m + __logf(__expf(l - m) + __expf(other - m));
  out[(size_t)63 * (B_ * 2) + b * 2 + cls] = l - ls;
}

extern "C" void kernel_launch(void* const* d_in, const int* in_sizes, int n_in,
                              void* d_out, int out_size, void* d_ws, size_t ws_size,
                              hipStream_t stream) {
  const int* x      = (const int*)d_in[0];
  const float* emb  = (const float*)d_in[1];
  const float* W_ih = (const float*)d_in[2];
  const float* W_hh = (const float*)d_in[3];
  const float* b_ih = (const float*)d_in[4];
  const float* b_hh = (const float*)d_in[5];
  const float* W_out = (const float*)d_in[6];
  const float* b_out = (const float*)d_in[7];
  const float* h0   = (const float*)d_in[8];
  const float* c0   = (const float*)d_in[9];
  float* out = (float*)d_out;

  // workspace (~186 MB; poison fills show d_ws >= 800MB)
  char* w = (char*)d_ws;
  u16* WihP = (u16*)w;   w += (size_t)G4_ * H_ * 2;             // 8 MB
  u16* WhhP = (u16*)w;   w += (size_t)G4_ * H_ * 2;             // 8 MB
  u16* XEc  = (u16*)w;   w += (size_t)CHUNK_ * HB_ * 2;         // 32 MB
  u16* GXc  = (u16*)w;   w += (size_t)CHUNK_ * B_ * G4_ * 2;    // 128 MB
  float* c  = (float*)w; w += (size_t)HB_ * 4;                  // 4 MB
  u16* hb   = (u16*)w;   w += (size_t)2 * HB_ * 2;              // 4 MB
  float* bcP = (float*)w;  w += (size_t)G4_ * 4;
  float* part = (float*)w; w += (size_t)2 * B_ * 2 * 64 * 4;    // 1 MB (double buffer)

  prep_kernel<<<5121, 256, 0, stream>>>(W_ih, W_hh, b_ih, b_hh, h0, c0,
                                        WihP, WhhP, bcP, hb, c);
  for (int ch = 0; ch < T_ / CHUNK_; ++ch) {
    gather_kernel<<<dim3(B_, CHUNK_), 256, 0, stream>>>(x, emb, XEc, ch * CHUNK_);
    xproj_kernel<<<4096, 256, 0, stream>>>(XEc, WihP, bcP, GXc);
    for (int tc = 0; tc < CHUNK_; ++tc) {
      int t = ch * CHUNK_ + tc;
      u16* hbR = hb + (size_t)(t & 1) * HB_;
      u16* hbW = hb + (size_t)((t + 1) & 1) * HB_;
      float* partW = part + (size_t)(t & 1) * (B_ * 2 * 64);
      float* partR = part + (size_t)((t + 1) & 1) * (B_ * 2 * 64);
      rec_kernel<<<512, 256, 0, stream>>>(hbR, WhhP, GXc + (size_t)tc * B_ * G4_,
                                          c, hbW, partW, partR, W_out, b_out, out, t);
    }
  }
  final_kernel<<<8, 256, 0, stream>>>(part + (size_t)(63 & 1) * (B_ * 2 * 64), b_out, out);
}

// Round 5
// 1723.860 us; speedup vs baseline: 1.8327x; 1.1617x over previous
//
#include <hip/hip_runtime.h>

typedef __bf16 bf16x8 __attribute__((ext_vector_type(8)));
typedef float f32x4 __attribute__((ext_vector_type(4)));
typedef unsigned short u16;
typedef unsigned int u32;

#define T_ 64
#define B_ 1024
#define H_ 1024
#define G4_ 4096
#define HB_ (B_ * H_)
#define CHUNK_ 16

__device__ inline u16 f2bf(float f) {
  u32 u = __float_as_uint(f);
  u32 r = (u + 0x7fffu + ((u >> 16) & 1u)) >> 16;  // RNE
  return (u16)r;
}

__device__ inline uint2 cvt4(float4 v) {
  uint2 r;
  r.x = (u32)f2bf(v.x) | ((u32)f2bf(v.y) << 16);
  r.y = (u32)f2bf(v.z) | ((u32)f2bf(v.w) << 16);
  return r;
}

__device__ __forceinline__ void gload16(const void* g, void* l) {
  __builtin_amdgcn_global_load_lds(
      (const __attribute__((address_space(1))) unsigned int*)g,
      (__attribute__((address_space(3))) unsigned int*)l, 16, 0, 0);
}

__device__ inline float fsig(float x) { return 1.f / (1.f + __expf(-x)); }
__device__ inline float ftanh(float x) {
  float e = __expf(2.f * x);
  return 1.f - 2.f / (e + 1.f);
}

// ---------- prep: WihP/WhhP gate-interleaved-row bf16 [4096][1024], bcP permuted bias,
// hb0=bf16(h0), c=c0.  Permutation: n' = (j>>4)*64 + gate*16 + (j&15)
__global__ void prep_kernel(const float* __restrict__ W_ih, const float* __restrict__ W_hh,
                            const float* __restrict__ b_ih, const float* __restrict__ b_hh,
                            const float* __restrict__ h0, const float* __restrict__ c0,
                            u16* __restrict__ WihP, u16* __restrict__ WhhP,
                            float* __restrict__ bcP, u16* __restrict__ hb0,
                            float* __restrict__ c) {
  int bid = blockIdx.x, tid = threadIdx.x;
  if (bid < 4096) {
    int np = bid;
    int gate = (np >> 4) & 3;
    int j = ((np >> 6) << 4) | (np & 15);
    size_t srow = (size_t)(gate * 1024 + j) * 1024;
    int base = tid << 2;
    *(uint2*)(WihP + (size_t)np * 1024 + base) = cvt4(*(const float4*)(W_ih + srow + base));
    *(uint2*)(WhhP + (size_t)np * 1024 + base) = cvt4(*(const float4*)(W_hh + srow + base));
  } else if (bid < 5120) {
    int i = ((bid - 4096) * 256 + tid) << 2;
    *(float4*)(c + i) = *(const float4*)(c0 + i);
    *(uint2*)(hb0 + i) = cvt4(*(const float4*)(h0 + i));
  } else {
#pragma unroll
    for (int q = 0; q < 16; ++q) {
      int np = q * 256 + tid;
      int gate = (np >> 4) & 3;
      int j = ((np >> 6) << 4) | (np & 15);
      int srcn = gate * 1024 + j;
      bcP[np] = b_ih[srcn] + b_hh[srcn];
    }
  }
}

// ---------- gather one chunk of 16 steps: XEc[tc][b][:] = bf16(emb[x[b, t0+tc]])
__global__ void gather_kernel(const int* __restrict__ x, const float* __restrict__ emb,
                              u16* __restrict__ XEc, int t0) {
  int b = blockIdx.x, tc = blockIdx.y;
  int row = x[b * T_ + t0 + tc];
  int e = threadIdx.x << 2;
  float4 v = *(const float4*)(emb + (size_t)row * H_ + e);
  *(uint2*)(XEc + ((size_t)tc * B_ + b) * H_ + e) = cvt4(v);
}

// ---------- x-projection big GEMM (128x128, 4 waves of 64x64, BK=64, LDS dbuf +
// counted vmcnt): GXc[gm][n'] = bf16( XEc[gm].WihP[n'] + bcP[n'] ).
// XCD mapping: per XCD, 4 m-groups of 4 m-tiles (1MB XE L2-resident), n-inner sweep.
__global__ void __launch_bounds__(256, 2) xproj_kernel(
    const u16* __restrict__ XEc, const u16* __restrict__ WihP,
    const float* __restrict__ bcP, u16* __restrict__ GXc) {
  __shared__ char smem[65536];  // A0 | A1 @16K | B0 @32K | B1 @48K
  const int tid = threadIdx.x;
  const int lane = tid & 63;
  const int wave = tid >> 6;
  const int wm = wave >> 1, wn = wave & 1;
  const int hbid = blockIdx.x;  // 4096 = 8 XCD x 512
  const int xcd = hbid & 7;
  const int s9 = hbid >> 3;           // [0,512)
  const int mg = s9 >> 7;             // 4 m-groups
  const int rem = s9 & 127;
  const int n0 = (rem >> 2) * 128;    // 32 n-tiles, inner sweep
  const int m0 = (xcd * 16 + mg * 4 + (rem & 3)) * 128;

  const u16* srcA[4];
  const u16* srcB[4];
  int betaA[4], betaB[4];
#pragma unroll
  for (int s = 0; s < 4; ++s) {
    int beta = (s * 256 + tid) * 16;             // 0..16K
    int row = beta >> 7;                         // 128B rows
    int colu = (beta & 127) ^ ((row & 7) << 4);  // pre-swizzled source col
    int kl = colu >> 1;
    srcA[s] = XEc + (size_t)(m0 + row) * 1024 + kl;
    srcB[s] = WihP + (size_t)(n0 + row) * 1024 + kl;
    betaA[s] = beta;
    betaB[s] = beta;
  }

  // prologue: tile 0 -> buf0
#pragma unroll
  for (int s = 0; s < 4; ++s) gload16(srcA[s], smem + betaA[s]);
#pragma unroll
  for (int s = 0; s < 4; ++s) gload16(srcB[s], smem + 32768 + betaB[s]);
#pragma unroll
  for (int s = 0; s < 4; ++s) { srcA[s] += 64; srcB[s] += 64; }

  f32x4 acc[4][4] = {};
  const int rsel = lane & 15;
  const int ksel = (lane >> 4) << 4;

#pragma unroll
  for (int kt = 0; kt < 16; ++kt) {
    const int cur = kt & 1;
    const int abase = cur * 16384;
    const int bbase = 32768 + cur * 16384;
    if (kt < 15) {
      const int nab = (cur ^ 1) * 16384;
      const int nbb = 32768 + (cur ^ 1) * 16384;
#pragma unroll
      for (int s = 0; s < 4; ++s) gload16(srcA[s], smem + nab + betaA[s]);
#pragma unroll
      for (int s = 0; s < 4; ++s) gload16(srcB[s], smem + nbb + betaB[s]);
#pragma unroll
      for (int s = 0; s < 4; ++s) { srcA[s] += 64; srcB[s] += 64; }
      asm volatile("s_waitcnt vmcnt(8)" ::: "memory");
    } else {
      asm volatile("s_waitcnt vmcnt(0)" ::: "memory");
    }
    __builtin_amdgcn_s_barrier();
    __builtin_amdgcn_sched_barrier(0);
#pragma unroll
    for (int kk = 0; kk < 2; ++kk) {
      const int colb = kk * 64 + ksel;
      bf16x8 af[4], bfr[4];
#pragma unroll
      for (int mi = 0; mi < 4; ++mi) {
        int row = wm * 64 + mi * 16 + rsel;
        af[mi] = *(const bf16x8*)(smem + abase + row * 128 + (colb ^ ((row & 7) << 4)));
      }
#pragma unroll
      for (int ni = 0; ni < 4; ++ni) {
        int row = wn * 64 + ni * 16 + rsel;
        bfr[ni] = *(const bf16x8*)(smem + bbase + row * 128 + (colb ^ ((row & 7) << 4)));
      }
#pragma unroll
      for (int mi = 0; mi < 4; ++mi)
#pragma unroll
        for (int ni = 0; ni < 4; ++ni)
          acc[mi][ni] = __builtin_amdgcn_mfma_f32_16x16x32_bf16(af[mi], bfr[ni], acc[mi][ni], 0, 0, 0);
    }
    __builtin_amdgcn_s_barrier();
    __builtin_amdgcn_sched_barrier(0);
  }

  const int rbase = (lane >> 4) << 2;
  const int cbase = lane & 15;
  float bc[4];
#pragma unroll
  for (int ni = 0; ni < 4; ++ni) bc[ni] = bcP[n0 + wn * 64 + ni * 16 + cbase];
#pragma unroll
  for (int mi = 0; mi < 4; ++mi) {
#pragma unroll
    for (int ni = 0; ni < 4; ++ni) {
      int gc = n0 + wn * 64 + ni * 16 + cbase;
#pragma unroll
      for (int r = 0; r < 4; ++r) {
        int gm = m0 + wm * 64 + mi * 16 + rbase + r;
        GXc[(size_t)gm * G4_ + gc] = f2bf(acc[mi][ni][r] + bc[ni]);
      }
    }
  }
}

// ---------- recurrent step: gates = GX(t) [LDS] + hbR @ WhhP^T, fused cell + head.
// 4 waves = 4 full-K M-slices (32x64 each, acc[2][4]); LDS dbuf + counted vmcnt.
__global__ void __launch_bounds__(256, 2) rec_kernel(
    const u16* __restrict__ hbR, const u16* __restrict__ WhhP,
    const u16* __restrict__ GXt, float* __restrict__ c, u16* __restrict__ hbW,
    float* __restrict__ partW, const float* __restrict__ partR,
    const float* __restrict__ Wout, const float* __restrict__ bout,
    float* __restrict__ out, int t) {
  __shared__ char smem[65536];  // A dbuf 2x16K | B dbuf 2x8K @32768 | GX 16K @49152
  const int tid = threadIdx.x;
  const int lane = tid & 63;
  const int qm = tid >> 6;  // wave = m-slice [0,4)
  const int hbid = blockIdx.x;
  const int L = (hbid & 7) * 64 + (hbid >> 3);  // XCD swizzle: W n-slice per XCD
  const int bx = L >> 3;   // [0,64): n-tile
  const int by = L & 7;    // [0,8): m-tile
  const int n0 = bx * 64;
  const int m0 = by * 128;

  // GX stage first (oldest in vmcnt queue)
#pragma unroll
  for (int s = 0; s < 4; ++s) {
    int beta = (s * 256 + tid) * 16;
    int row = beta >> 7;
    int colu = (beta & 127) ^ ((row & 7) << 4);
    gload16(GXt + (size_t)(m0 + row) * G4_ + n0 + (colu >> 1), smem + 49152 + beta);
  }

  const u16* srcA[4];
  const u16* srcB[2];
  int betaA[4], betaB[2];
#pragma unroll
  for (int s = 0; s < 4; ++s) {
    int beta = (s * 256 + tid) * 16;  // 0..16K, rows [128][128B]
    int row = beta >> 7;
    int colu = (beta & 127) ^ ((row & 7) << 4);
    srcA[s] = hbR + (size_t)(m0 + row) * 1024 + (colu >> 1);
    betaA[s] = beta;
  }
#pragma unroll
  for (int s = 0; s < 2; ++s) {
    int beta = (s * 256 + tid) * 16;  // 0..8K, rows [64][128B]
    int row = beta >> 7;
    int colu = (beta & 127) ^ ((row & 7) << 4);
    srcB[s] = WhhP + (size_t)(n0 + row) * 1024 + (colu >> 1);
    betaB[s] = beta;
  }

  // prologue: tile 0 -> buf0
#pragma unroll
  for (int s = 0; s < 4; ++s) gload16(srcA[s], smem + betaA[s]);
#pragma unroll
  for (int s = 0; s < 2; ++s) gload16(srcB[s], smem + 32768 + betaB[s]);
#pragma unroll
  for (int s = 0; s < 4; ++s) srcA[s] += 64;
#pragma unroll
  for (int s = 0; s < 2; ++s) srcB[s] += 64;

  f32x4 acc[2][4] = {};
  const int rsel = lane & 15;
  const int ksel = (lane >> 4) << 4;

#pragma unroll
  for (int kt = 0; kt < 16; ++kt) {
    const int cur = kt & 1;
    const int abase = cur * 16384;
    const int bbase = 32768 + cur * 8192;
    if (kt < 15) {
      const int nab = (cur ^ 1) * 16384;
      const int nbb = 32768 + (cur ^ 1) * 8192;
#pragma unroll
      for (int s = 0; s < 4; ++s) gload16(srcA[s], smem + nab + betaA[s]);
#pragma unroll
      for (int s = 0; s < 2; ++s) gload16(srcB[s], smem + nbb + betaB[s]);
#pragma unroll
      for (int s = 0; s < 4; ++s) srcA[s] += 64;
#pragma unroll
      for (int s = 0; s < 2; ++s) srcB[s] += 64;
      asm volatile("s_waitcnt vmcnt(6)" ::: "memory");
    } else {
      asm volatile("s_waitcnt vmcnt(0)" ::: "memory");
    }
    __builtin_amdgcn_s_barrier();
    __builtin_amdgcn_sched_barrier(0);
#pragma unroll
    for (int kk = 0; kk < 2; ++kk) {
      const int colb = kk * 64 + ksel;
      bf16x8 af[2], bfr[4];
#pragma unroll
      for (int mi = 0; mi < 2; ++mi) {
        int row = qm * 32 + mi * 16 + rsel;
        af[mi] = *(const bf16x8*)(smem + abase + row * 128 + (colb ^ ((row & 7) << 4)));
      }
#pragma unroll
      for (int ni = 0; ni < 4; ++ni) {
        int row = ni * 16 + rsel;
        bfr[ni] = *(const bf16x8*)(smem + bbase + row * 128 + (colb ^ ((row & 7) << 4)));
      }
#pragma unroll
      for (int mi = 0; mi < 2; ++mi)
#pragma unroll
        for (int ni = 0; ni < 4; ++ni)
          acc[mi][ni] = __builtin_amdgcn_mfma_f32_16x16x32_bf16(af[mi], bfr[ni], acc[mi][ni], 0, 0, 0);
    }
    __builtin_amdgcn_s_barrier();
    __builtin_amdgcn_sched_barrier(0);
  }

  // epilogue: gates = acc + GX(LDS); cell; head partials. All 4 waves participate.
  const char* lsGX = smem + 49152;
  const int rbase = (lane >> 4) << 2;
  const int cbase = lane & 15;
  const int j = bx * 16 + cbase;
  const float w0 = Wout[j], w1 = Wout[1024 + j];
#pragma unroll
  for (int mi = 0; mi < 2; ++mi) {
#pragma unroll
    for (int r = 0; r < 4; ++r) {
      int grow = qm * 32 + mi * 16 + rbase + r;  // row within 128-tile
      int b = m0 + grow;
      int gxswz = (grow & 7) << 4;
      float gx0 = __uint_as_float(
          (u32)*(const u16*)(lsGX + ((grow << 7) | ((cbase << 1) ^ gxswz))) << 16);
      float gx1 = __uint_as_float(
          (u32)*(const u16*)(lsGX + ((grow << 7) | ((((16 + cbase) << 1)) ^ gxswz))) << 16);
      float gx2 = __uint_as_float(
          (u32)*(const u16*)(lsGX + ((grow << 7) | ((((32 + cbase) << 1)) ^ gxswz))) << 16);
      float gx3 = __uint_as_float(
          (u32)*(const u16*)(lsGX + ((grow << 7) | ((((48 + cbase) << 1)) ^ gxswz))) << 16);
      float gi = acc[mi][0][r] + gx0;
      float gf = acc[mi][1][r] + gx1;
      float gg = acc[mi][2][r] + gx2;
      float go = acc[mi][3][r] + gx3;
      size_t idx = (size_t)b * H_ + j;
      float c2 = fsig(gf) * c[idx] + fsig(gi) * ftanh(gg);
      float h2 = fsig(go) * ftanh(c2);
      c[idx] = c2;
      hbW[idx] = f2bf(h2);
      float p0 = c2 * w0, p1 = c2 * w1;
#pragma unroll
      for (int off = 1; off < 16; off <<= 1) {
        p0 += __shfl_xor(p0, off);
        p1 += __shfl_xor(p1, off);
      }
      if (cbase == 0) {
        partW[(b << 7) + bx] = p0;
        partW[(b << 7) + 64 + bx] = p1;
      }
    }
  }

  // finalize previous step's head (off critical path)
  if (t > 0 && by == 0 && tid < 32) {
    int b = bx * 16 + (tid >> 1);
    int cls = tid & 1;
    const float4* pp = (const float4*)(partR + (b << 7) + cls * 64);
    float4 sv = {0.f, 0.f, 0.f, 0.f};
#pragma unroll
    for (int q = 0; q < 16; ++q) {
      float4 v = pp[q];
      sv.x += v.x; sv.y += v.y; sv.z += v.z; sv.w += v.w;
    }
    float l = sv.x + sv.y + sv.z + sv.w + bout[cls];
    float other = __shfl_xor(l, 1);
    float m = fmaxf(l, other);
    float ls = m + __logf(__expf(l - m) + __expf(other - m));
    out[(size_t)(t - 1) * (B_ * 2) + b * 2 + cls] = l - ls;
  }
}

// ---------- final: reduce step-63 partials -> out[63] (log-softmax) + out_final (raw)
__global__ void final_kernel(const float* __restrict__ partR, const float* __restrict__ bout,
                             float* __restrict__ out) {
  int gid = blockIdx.x * 256 + threadIdx.x;  // 2048 = 1024 b x 2 cls
  int b = gid >> 1, cls = gid & 1;
  const float4* pp = (const float4*)(partR + (b << 7) + cls * 64);
  float4 sv = {0.f, 0.f, 0.f, 0.f};
#pragma unroll
  for (int q = 0; q < 16; ++q) {
    float4 v = pp[q];
    sv.x += v.x; sv.y += v.y; sv.z += v.z; sv.w += v.w;
  }
  float l = sv.x + sv.y + sv.z + sv.w + bout[cls];
  out[(size_t)T_ * (B_ * 2) + b * 2 + cls] = l;  // out_final raw
  float other = __shfl_xor(l, 1);
  float m = fmaxf(l, other);
  float ls = m + __logf(__expf(l - m) + __expf(other - m));
  out[(size_t)63 * (B_ * 2) + b * 2 + cls] = l - ls;
}

extern "C" void kernel_launch(void* const* d_in, const int* in_sizes, int n_in,
                              void* d_out, int out_size, void* d_ws, size_t ws_size,
                              hipStream_t stream) {
  const int* x      = (const int*)d_in[0];
  const float* emb  = (const float*)d_in[1];
  const float* W_ih = (const float*)d_in[2];
  const float* W_hh = (const float*)d_in[3];
  const float* b_ih = (const float*)d_in[4];
  const float* b_hh = (const float*)d_in[5];
  const float* W_out = (const float*)d_in[6];
  const float* b_out = (const float*)d_in[7];
  const float* h0   = (const float*)d_in[8];
  const float* c0   = (const float*)d_in[9];
  float* out = (float*)d_out;

  // workspace (~186 MB)
  char* w = (char*)d_ws;
  u16* WihP = (u16*)w;   w += (size_t)G4_ * H_ * 2;             // 8 MB
  u16* WhhP = (u16*)w;   w += (size_t)G4_ * H_ * 2;             // 8 MB
  u16* XEc  = (u16*)w;   w += (size_t)CHUNK_ * HB_ * 2;         // 32 MB
  u16* GXc  = (u16*)w;   w += (size_t)CHUNK_ * B_ * G4_ * 2;    // 128 MB
  float* c  = (float*)w; w += (size_t)HB_ * 4;                  // 4 MB
  u16* hb   = (u16*)w;   w += (size_t)2 * HB_ * 2;              // 4 MB
  float* bcP = (float*)w;  w += (size_t)G4_ * 4;
  float* part = (float*)w; w += (size_t)2 * B_ * 2 * 64 * 4;    // 1 MB (double buffer)

  prep_kernel<<<5121, 256, 0, stream>>>(W_ih, W_hh, b_ih, b_hh, h0, c0,
                                        WihP, WhhP, bcP, hb, c);
  for (int ch = 0; ch < T_ / CHUNK_; ++ch) {
    gather_kernel<<<dim3(B_, CHUNK_), 256, 0, stream>>>(x, emb, XEc, ch * CHUNK_);
    xproj_kernel<<<4096, 256, 0, stream>>>(XEc, WihP, bcP, GXc);
    for (int tc = 0; tc < CHUNK_; ++tc) {
      int t = ch * CHUNK_ + tc;
      u16* hbR = hb + (size_t)(t & 1) * HB_;
      u16* hbW = hb + (size_t)((t + 1) & 1) * HB_;
      float* partW = part + (size_t)(t & 1) * (B_ * 2 * 64);
      float* partR = part + (size_t)((t + 1) & 1) * (B_ * 2 * 64);
      rec_kernel<<<512, 256, 0, stream>>>(hbR, WhhP, GXc + (size_t)tc * B_ * G4_,
                                          c, hbW, partW, partR, W_out, b_out, out, t);
    }
  }
  final_kernel<<<8, 256, 0, stream>>>(part + (size_t)(63 & 1) * (B_ * 2 * 64), b_out, out);
}